// Round 5
// baseline (549.611 us; speedup 1.0000x reference)
//
#include <hip/hip_runtime.h>
#include <cstddef>

// ---------- helpers ----------
typedef __bf16 bf16x8 __attribute__((ext_vector_type(8)));
typedef float  floatx4 __attribute__((ext_vector_type(4)));

static __device__ __forceinline__ unsigned short f2bf(float f) {
    unsigned int u = __float_as_uint(f);
    u = u + 0x7fff + ((u >> 16) & 1);   // round-to-nearest-even
    return (unsigned short)(u >> 16);
}
static __device__ __forceinline__ float bflo(unsigned int u) {
    return __uint_as_float(u << 16);
}
static __device__ __forceinline__ float bfhi(unsigned int u) {
    return __uint_as_float(u & 0xffff0000u);
}

// ---------- kernel 1: W1 fp32 -> bf16 (proven, unchanged) ----------
__global__ __launch_bounds__(256) void nnue_convw1(
    const float* __restrict__ W1, unsigned short* __restrict__ W1b)
{
    const int i = (blockIdx.x * 256 + threadIdx.x) * 4;
    const float4 v = *reinterpret_cast<const float4*>(W1 + i);
    ushort4 o;
    o.x = f2bf(v.x); o.y = f2bf(v.y); o.z = f2bf(v.z); o.w = f2bf(v.w);
    *reinterpret_cast<ushort4*>(W1b + i) = o;
}

// ---------- kernel 2: P = emb @ W1cat^T ----------
// GEMM M=40960 N=256 K=2048. BM=128, BN=256 (A read ONCE), BK=64; grid 320.
// 512 threads = 8 waves (2m x 4n), wave tile 64x64 -> 0.5 ds_reads/MFMA.
// BOTH operands direct-to-LDS via global_load_lds (no staging VALU):
//   B: bf16 [256][64], 16B-unit swizzle u ^= (row&7)   (round-2 PROVEN path)
//   A: fp32 [128][64], same 16B-unit swizzle u ^= (row&7); converted to
//      bf16 at fragment-read time ((__bf16) casts -> v_cvt_pk_bf16_f32).
// Source pre-swizzle + read-side XOR = same involution both sides (rule #21).
// Fragment conventions identical to the proven round-1 MFMA kernel.
__global__ __launch_bounds__(512) void nnue_pgemm(
    const float* __restrict__ emb, const unsigned short* __restrict__ w1b,
    unsigned short* __restrict__ P)
{
    __shared__ float          Asf[128 * 64];   // 32 KB (swizzled fp32)
    __shared__ unsigned short Bs[256 * 64];    // 32 KB (swizzled bf16)

    const int t    = threadIdx.x;
    const int wid  = t >> 6;
    const int lane = t & 63;
    const int quad = lane >> 4;
    const int l16  = lane & 15;
    const int wm   = wid >> 2;      // 0..1
    const int wn   = wid & 3;       // 0..3
    const int fbase = blockIdx.x * 128;

    // B DMA: chunk = 8 rows x 128 B. lane covers row (lane>>3), 16B-unit (lane&7).
    const int bRow       = lane >> 3;
    const int bSrcShorts = (((lane & 7) ^ bRow) << 3);   // unit ^ (row&7), in shorts
    // A DMA: chunk = 4 rows x 256 B. lane covers row (lane>>4), 16B-unit (lane&15).
    const int aRowIn     = lane >> 4;
    const int aUnit      = lane & 15;

    floatx4 acc[4][4];
#pragma unroll
    for (int i = 0; i < 4; ++i)
#pragma unroll
        for (int j = 0; j < 4; ++j) acc[i][j] = (floatx4){0.f, 0.f, 0.f, 0.f};

    for (int kc = 0; kc < 2048; kc += 64) {
        __syncthreads();
        // --- stage A (32 chunks) + B (32 chunks); wave wid owns 4 of each
#pragma unroll
        for (int i = 0; i < 4; ++i) {
            const int cA = wid * 4 + i;
            const int rA = cA * 4 + aRowIn;                       // 0..127
            const int uA = aUnit ^ (rA & 7);                      // src 16B-unit
            const float* gA = emb + (size_t)(fbase + rA) * 2048 + kc + uA * 4;
            auto* dA = (__attribute__((address_space(3))) unsigned int*)(Asf + cA * 256);
            __builtin_amdgcn_global_load_lds(
                (const __attribute__((address_space(1))) unsigned int*)gA, dA, 16, 0, 0);

            const int cB = wid * 4 + i;
            const int rB = cB * 8 + bRow;                         // 0..255
            const unsigned short* gB = w1b + (size_t)(rB & 127) * 4096
                                     + (rB >> 7) * 2048 + kc + bSrcShorts;
            auto* dB = (__attribute__((address_space(3))) unsigned int*)(Bs + cB * 512);
            __builtin_amdgcn_global_load_lds(
                (const __attribute__((address_space(1))) unsigned int*)gB, dB, 16, 0, 0);
        }
        __syncthreads();   // compiler drains vmcnt (DMA) before barrier
        // --- compute: wave tile 64x64
#pragma unroll
        for (int kk = 0; kk < 64; kk += 32) {
            bf16x8 a[4], b[4];
#pragma unroll
            for (int mi = 0; mi < 4; ++mi) {
                const int row = wm * 64 + mi * 16 + l16;
                const int cb0 = kk * 4 + quad * 32;               // byte col in row
                const char* base = reinterpret_cast<const char*>(Asf) + row * 256;
                const float4 lo = *reinterpret_cast<const float4*>(
                    base + ((cb0)      ^ ((row & 7) << 4)));
                const float4 hi = *reinterpret_cast<const float4*>(
                    base + ((cb0 + 16) ^ ((row & 7) << 4)));
                bf16x8 av;
                av[0] = (__bf16)lo.x; av[1] = (__bf16)lo.y;
                av[2] = (__bf16)lo.z; av[3] = (__bf16)lo.w;
                av[4] = (__bf16)hi.x; av[5] = (__bf16)hi.y;
                av[6] = (__bf16)hi.z; av[7] = (__bf16)hi.w;
                a[mi] = av;
            }
#pragma unroll
            for (int ni = 0; ni < 4; ++ni) {
                const int r  = wn * 64 + ni * 16 + l16;
                const int cb = (kk * 2 + quad * 16) ^ ((r & 7) << 4);
                b[ni] = *reinterpret_cast<const bf16x8*>(
                    reinterpret_cast<const char*>(Bs) + r * 128 + cb);
            }
#pragma unroll
            for (int mi = 0; mi < 4; ++mi)
#pragma unroll
                for (int ni = 0; ni < 4; ++ni)
                    acc[mi][ni] = __builtin_amdgcn_mfma_f32_16x16x32_bf16(
                        a[mi], b[ni], acc[mi][ni], 0, 0, 0);
        }
    }

    // write P (bf16). D element: m = quad*4+r (within 16-block), n = l16.
#pragma unroll
    for (int mi = 0; mi < 4; ++mi)
#pragma unroll
        for (int ni = 0; ni < 4; ++ni) {
            const int n = wn * 64 + ni * 16 + l16;
#pragma unroll
            for (int r = 0; r < 4; ++r) {
                const int f = fbase + wm * 64 + mi * 16 + quad * 4 + r;
                P[(size_t)f * 256 + n] = f2bf(acc[mi][ni][r]);
            }
        }
}

// ---------- kernel 3: gather P rows + fused epilogue ----------
// v2: TWO waves per batch element (white-wave / black-wave), combined
// pre-ReLU through LDS. Halves the per-wave serial gather chain (64->32)
// and doubles wave-level parallelism. Math identical to proven v1.
__global__ __launch_bounds__(256) void nnue_out(
    const int* __restrict__ white, const int* __restrict__ black,
    const int* __restrict__ stm, const unsigned short* __restrict__ P,
    const float* __restrict__ b1, const float* __restrict__ W2,
    const float* __restrict__ b2, float* __restrict__ out)
{
    __shared__ int sW[64], sB[64];
    __shared__ float red[4][64][2];
    const int t = threadIdx.x;
    const int bbase = blockIdx.x * 2;              // 2 batch elements per block
    if (t < 64)       sW[t] = white[bbase * 32 + t];
    else if (t < 128) sB[t - 64] = black[bbase * 32 + (t - 64)];
    __syncthreads();

    const int w = t >> 6, lane = t & 63;
    const int pair = w >> 1;                       // 0..1 : which batch element
    const int b = bbase + pair;
    const bool isW = ((w & 1) == 0);
    const int stm_b = stm[b];
    // stm==1: x=[white,black] -> white uses cols 0..127, black 128..255
    const int off = isW ? ((stm_b != 0) ? 0 : 128)
                        : ((stm_b != 0) ? 128 : 0);
    const int* lst = isW ? (sW + pair * 32) : (sB + pair * 32);
    const int n2 = lane * 2;

    float h0 = 0.f, h1 = 0.f;
#pragma unroll
    for (int i = 0; i < 32; ++i) {
        const int idx = lst[i];
        const unsigned int u = *reinterpret_cast<const unsigned int*>(
            P + (size_t)idx * 256 + off + n2);
        const float m = (idx != 0) ? 1.f : 0.f;    // index 0 = padding
        h0 += bflo(u) * m;
        h1 += bfhi(u) * m;
    }
    red[w][lane][0] = h0;
    red[w][lane][1] = h1;
    __syncthreads();

    if (isW) {   // waves 0,2 finalize their batch element
        float H0 = red[w][lane][0] + red[w + 1][lane][0] + b1[n2];
        float H1 = red[w][lane][1] + red[w + 1][lane][1] + b1[n2 + 1];
        H0 = (H0 > 0.f) ? H0 : 0.f;
        H1 = (H1 > 0.f) ? H1 : 0.f;
        float s = H0 * W2[n2] + H1 * W2[n2 + 1];
#pragma unroll
        for (int m = 1; m < 64; m <<= 1) s += __shfl_xor(s, m, 64);
        if (lane == 0) out[b] = s + b2[0];
    }
}

// ---------- launcher ----------
extern "C" void kernel_launch(void* const* d_in, const int* in_sizes, int n_in,
                              void* d_out, int out_size, void* d_ws, size_t ws_size,
                              hipStream_t stream)
{
    const int*   white = (const int*)d_in[0];
    const int*   black = (const int*)d_in[1];
    const int*   stm   = (const int*)d_in[2];
    const float* emb   = (const float*)d_in[3];
    const float* W1    = (const float*)d_in[4];
    const float* b1    = (const float*)d_in[5];
    const float* W2    = (const float*)d_in[6];
    const float* b2    = (const float*)d_in[7];
    float* out = (float*)d_out;

    unsigned short* w1buf = (unsigned short*)d_ws;                 // 128*4096 bf16 = 1 MiB
    unsigned short* pbuf  = w1buf + (size_t)128 * 4096;            // 40960*256 bf16 = 20 MiB

    nnue_convw1<<<512, 256, 0, stream>>>(W1, w1buf);
    nnue_pgemm<<<320, 512, 0, stream>>>(emb, w1buf, pbuf);
    nnue_out<<<2048, 256, 0, stream>>>(white, black, stm, pbuf, b1, W2, b2, out);
}